// Round 1
// baseline (3253.469 us; speedup 1.0000x reference)
//
#include <hip/hip_runtime.h>
#include <stdint.h>

#define NB 16
#define HH 128
#define WW 128
#define L (HH*WW)        // 16384
#define CIN 3
#define HID 256
#define NC 21
#define CHUNK 256
#define NCHUNKS (L/CHUNK)   // 64
#define T_PER 32            // t's per wave in k_bp
#define NPACK (L/4)         // 4096 packs of 4 timesteps

// ---------------- K1: conv -> fp32 emissions, TRANSPOSED em_T[b][c][t], LDS input tile ----------------
// fp64 accumulate (round once to fp32 = correctly rounded), fp32 elementwise bias in ref order.
// Block covers 2 image rows; x patch staged in LDS (6 coalesced loads/thread vs 27 global).
// Values and FMA order identical to R16 -> bit-identical emissions.
__global__ __launch_bounds__(256) void k_conv(
    const float* __restrict__ x, const float* __restrict__ w1,
    const float* __restrict__ b1, const float* __restrict__ w2,
    const float* __restrict__ b2, float* __restrict__ emT)
{
    __shared__ float xs[CIN*4*WW];        // 3 ic x 4 rows x 128 cols = 6144 B
    int tid = threadIdx.x;
    int g  = blockIdx.x * 256 + tid;      // 0..B*L-1
    int b  = g >> 14;
    int t0 = (blockIdx.x * 256) & (L-1);  // first t of block (multiple of 256)
    int y0 = t0 >> 7;                     // first of the block's 2 rows
    int dy = tid >> 7;                    // 0 or 1
    int y  = y0 + dy;
    int xx = tid & (WW-1);
    int t  = t0 + tid;

    const float* xb = x + (size_t)b * CIN * L;
    for (int i = tid; i < CIN*4*WW; i += 256) {
        int ic  = i >> 9;                 // /512
        int rem = i & 511;
        int rr  = rem >> 7;               // 0..3
        int cc  = rem & 127;
        int row = y0 - 1 + rr;
        xs[i] = (row >= 0 && row < HH) ? xb[ic*L + (row<<7) + cc] : 0.f;
    }
    __syncthreads();

    double p[27];
    #pragma unroll
    for (int ic = 0; ic < CIN; ++ic) {
        #pragma unroll
        for (int ky = 0; ky < 3; ++ky) {
            #pragma unroll
            for (int kx = 0; kx < 3; ++kx) {
                int xc = xx + kx - 1;
                float v = (xc >= 0 && xc < WW) ? xs[ic*512 + (dy+ky)*128 + xc] : 0.f;
                p[ic*9 + ky*3 + kx] = (double)v;
            }
        }
    }

    double acc[NC];
    #pragma unroll
    for (int c = 0; c < NC; ++c) acc[c] = 0.0;

    #pragma unroll 2
    for (int oc = 0; oc < HID; ++oc) {
        double hv = 0.0;                              // conv1 accum
        #pragma unroll
        for (int j = 0; j < 27; ++j) hv += (double)w1[oc*27 + j] * p[j];
        float h32 = (float)hv;                        // round conv1 to fp32
        h32 = h32 + b1[oc];                           // fp32 elementwise bias
        h32 = fmaxf(h32, 0.f);                        // relu (fp32)
        double hd = (double)h32;
        #pragma unroll
        for (int c = 0; c < NC; ++c) acc[c] += (double)w2[c*HID + oc] * hd;
    }
    float* dstb = emT + (size_t)b * NC * L;
    #pragma unroll
    for (int c = 0; c < NC; ++c) {
        float e32 = (float)acc[c];                    // round conv2 to fp32
        dstb[(size_t)c * L + t] = e32 + b2[c];        // transposed store (coalesced in t)
    }
}

// ---------------- K2a: readlane-broadcast full-rank recursion (no DS ops on the chain) ----------------
// s'[n] = fl( max_p fl(s[p]+T[p][n]) + e[n] ) — bitwise equal to ref (same adds, exact max, same
// final add; max is association-invariant).
// Old structure: 9 ds_bpermute/step = 2 dependent DS round-trips (~2x120cy) -> 314 cyc/step.
// New: 21 v_readlane (SGPR broadcast, pure VALU) + 21 v_add(v,s,v) + max3 tree + 1 add
// = ~53 VALU instr/step, zero LDS ops on the critical path. Est ~90-130 cyc/step.
__global__ __launch_bounds__(64) void k_scores(
    const float* __restrict__ emT, const float* __restrict__ start,
    const float* __restrict__ endt, const float* __restrict__ trans,
    float* __restrict__ sc, int* __restrict__ last_tag)
{
    __shared__ float fin[NC];
    int l = threadIdx.x;
    int b = blockIdx.x;
    int n = l < NC ? l : NC-1;            // lanes 21..63 shadow n=20 (results unused)

    const float4* er4 = (const float4*)(emT + ((size_t)b * NC + n) * L);
    float*        scp = sc + (size_t)b * NC * L;          // 84 floats per pack

    float tc[NC];                          // T[p][n] for my n, p = 0..20
    #pragma unroll
    for (int p = 0; p < NC; ++p) tc[p] = trans[p*NC + n];
    #pragma unroll
    for (int p = 0; p < NC; ++p) asm volatile("" : "+v"(tc[p]));   // pin in VGPRs

    float sv;   // my state's current score s[n] (lane n holds s[n])

    #define RL(I) __int_as_float(__builtin_amdgcn_readlane(si, (I)))

    #define STEP(EV, OUT) { \
        int si = __float_as_int(sv); \
        float w0  = RL(0)  + tc[0];  \
        float w1  = RL(1)  + tc[1];  \
        float w2  = RL(2)  + tc[2];  \
        float w3  = RL(3)  + tc[3];  \
        float w4  = RL(4)  + tc[4];  \
        float w5  = RL(5)  + tc[5];  \
        float w6  = RL(6)  + tc[6];  \
        float w7  = RL(7)  + tc[7];  \
        float w8  = RL(8)  + tc[8];  \
        float w9  = RL(9)  + tc[9];  \
        float w10 = RL(10) + tc[10]; \
        float w11 = RL(11) + tc[11]; \
        float w12 = RL(12) + tc[12]; \
        float w13 = RL(13) + tc[13]; \
        float w14 = RL(14) + tc[14]; \
        float w15 = RL(15) + tc[15]; \
        float w16 = RL(16) + tc[16]; \
        float w17 = RL(17) + tc[17]; \
        float w18 = RL(18) + tc[18]; \
        float w19 = RL(19) + tc[19]; \
        float w20 = RL(20) + tc[20]; \
        float m0 = fmaxf(fmaxf(w0,  w1),  w2);   /* v_max3 */ \
        float m1 = fmaxf(fmaxf(w3,  w4),  w5);  \
        float m2 = fmaxf(fmaxf(w6,  w7),  w8);  \
        float m3 = fmaxf(fmaxf(w9,  w10), w11); \
        float m4 = fmaxf(fmaxf(w12, w13), w14); \
        float m5 = fmaxf(fmaxf(w15, w16), w17); \
        float m6 = fmaxf(fmaxf(w18, w19), w20); \
        float q0 = fmaxf(fmaxf(m0, m1), m2); \
        float q1 = fmaxf(fmaxf(m3, m4), m5); \
        float pr = fmaxf(fmaxf(q0, q1), m6);     /* exact max over 21 */ \
        OUT = pr + (EV);                         /* fl(+e) */ \
        sv = OUT; }

    float4 ebuf0 = er4[0];
    float4 ebuf1 = er4[1];

    // ---- pack 0 (t=0 init + t=1..3) ----
    float v0 = ebuf0.x + start[n];      // s0 = fl(em[0]+start), ref order
    sv = v0;
    {
        float4 ev = ebuf0;
        ebuf0 = er4[2];
        float a1v, a2v, a3v;
        STEP(ev.y, a1v)
        STEP(ev.z, a2v)
        STEP(ev.w, a3v)
        if (l < NC) *(float4*)(scp + n*4) = make_float4(v0, a1v, a2v, a3v);
    }

    // ---- packs 1..4095 ----
    for (int k = 1; k < NPACK; ++k) {
        float4 ev = (k & 1) ? ebuf1 : ebuf0;
        int kp = k + 2; if (kp > NPACK-1) kp = NPACK-1;
        if (k & 1) ebuf1 = er4[kp]; else ebuf0 = er4[kp];

        float b0, b1_, b2_, b3;
        STEP(ev.x, b0)
        STEP(ev.y, b1_)
        STEP(ev.z, b2_)
        STEP(ev.w, b3)
        if (l < NC) *(float4*)(scp + k*84 + n*4) = make_float4(b0, b1_, b2_, b3);
    }
    #undef STEP
    #undef RL

    if (l < NC) fin[n] = sv;
    __syncthreads();
    if (l == 0) {
        float bv = fin[0] + endt[0]; int bt = 0;
        #pragma unroll
        for (int j = 1; j < NC; ++j) {
            float v = fin[j] + endt[j];
            if (v > bv) { bv = v; bt = j; }
        }
        last_tag[b] = bt;
    }
}

// ---------------- K2b: parallel backpointer recovery ----------------
// bp[t][n] = first p with fl(fl(s_{t-1}[p]+T[p][n])+e[t][n]) == s_t[n]
__global__ __launch_bounds__(256) void k_bp(
    const float* __restrict__ emT, const float* __restrict__ sc,
    const float* __restrict__ trans, uint8_t* __restrict__ bp)
{
    int wave = threadIdx.x >> 6;
    int lane = threadIdx.x & 63;
    int ne   = lane < NC ? lane : NC-1;

    int bidx  = blockIdx.x;
    int b     = bidx >> 7;                              // 128 blocks per batch
    int tbase = (bidx & 127) * (4*T_PER) + wave*T_PER;

    const float* emb = emT + (size_t)b * NC * L;
    const float* scp = sc  + (size_t)b * NC * L;
    uint8_t*     bpb = bp  + (size_t)b * L * NC;

    float tc[NC];
    #pragma unroll
    for (int pp = 0; pp < NC; ++pp) tc[pp] = trans[pp*NC + ne];

    for (int t = tbase; t < tbase + T_PER; ++t) {
        if (t == 0) continue;
        float target = scp[(t>>2)*84 + ne*4 + (t&3)];
        float e      = emb[(size_t)ne * L + t];
        const float* sp = scp + ((t-1)>>2)*84 + ((t-1)&3);
        int fi = 0;
        #pragma unroll
        for (int pp = NC-1; pp >= 0; --pp) {
            float cand = (sp[pp*4] + tc[pp]) + e;
            if (cand == target) fi = pp;
        }
        if (lane < NC) bpb[(size_t)t * NC + ne] = (uint8_t)fi;
    }
}

// ---------------- K3a: per-chunk jump tables, SEGMENTED chase (exact) ----------------
// 8 segment tables of 32 hops built by 63 lanes (3 pipelined chases/lane), composed in 8 hops.
// Wall ~ 32+8 dependent LDS hops vs 256 before.
__global__ __launch_bounds__(64) void k_jump(
    const uint8_t* __restrict__ bp, uint8_t* __restrict__ J)
{
    __shared__ uint32_t lds4[CHUNK*NC/4];    // 5376 B of bp rows [cs..ce)
    __shared__ uint8_t  segJ[8*NC];          // 168 B
    int l   = threadIdx.x;
    int bid = blockIdx.x;
    int b   = bid / (NCHUNKS-1);
    int k   = bid % (NCHUNKS-1) + 1;         // chunks 1..63
    int cs  = k * CHUNK;

    const uint32_t* src = (const uint32_t*)(bp + (size_t)b * L * NC + (size_t)cs * NC);
    for (int i = l; i < CHUNK*NC/4; i += 64) lds4[i] = src[i];
    __syncthreads();
    const uint8_t* lb = (const uint8_t*)lds4;

    // 168 = 8 segs x 21 hyps; chase c -> (s=c/21, h=c%21), rows s*32+31 .. s*32
    int c0 = l, c1 = l + 63, c2 = l + 126;
    bool v2 = (c2 < 8*NC);
    int t0 = c0 % NC, t1 = c1 % NC, t2 = v2 ? (c2 % NC) : 0;
    int r0 = (c0 / NC) * 32, r1 = (c1 / NC) * 32, r2 = v2 ? (c2 / NC) * 32 : 0;
    for (int i = 31; i >= 0; --i) {          // 3 independent chains -> pipelined
        t0 = lb[(r0+i)*NC + t0];
        t1 = lb[(r1+i)*NC + t1];
        if (v2) t2 = lb[(r2+i)*NC + t2];
    }
    segJ[c0] = (uint8_t)t0;
    segJ[c1] = (uint8_t)t1;
    if (v2) segJ[c2] = (uint8_t)t2;
    __syncthreads();

    if (l < NC) {
        int tag = l;
        #pragma unroll
        for (int s = 7; s >= 0; --s) tag = segJ[s*NC + tag];
        J[((size_t)b * NCHUNKS + k) * NC + l] = (uint8_t)tag;
    }
}

// ---------------- K3b: thread chunk entries through jump tables (LDS-staged J) ----------------
__global__ __launch_bounds__(64) void k_seq(
    const uint8_t* __restrict__ J, const int* __restrict__ last_tag,
    uint8_t* __restrict__ ent)
{
    __shared__ uint32_t ldsJ4[NB*NCHUNKS*NC/4];   // 21504 B
    int l = threadIdx.x;
    const uint32_t* src = (const uint32_t*)J;
    for (int i = l; i < NB*NCHUNKS*NC/4; i += 64) ldsJ4[i] = src[i];
    __syncthreads();
    const uint8_t* lj = (const uint8_t*)ldsJ4;

    if (l < NB) {
        int b = l;
        int tag = last_tag[b];                       // tag at t = L-1
        ent[b * NCHUNKS + 63] = (uint8_t)tag;
        for (int k = NCHUNKS-1; k >= 1; --k) {
            tag = lj[((size_t)b * NCHUNKS + k) * NC + tag];
            ent[b * NCHUNKS + (k-1)] = (uint8_t)tag;
        }
    }
}

// ---------------- K3c: per-chunk output, SEGMENTED re-walk from exact seed ----------------
__global__ __launch_bounds__(64) void k_out(
    const uint8_t* __restrict__ bp, const uint8_t* __restrict__ ent,
    int* __restrict__ out)
{
    __shared__ uint32_t lds4[CHUNK*NC/4];
    __shared__ uint8_t  segJ[8*NC];
    __shared__ uint8_t  E[8];
    __shared__ int      tags[CHUNK];
    int l   = threadIdx.x;
    int bid = blockIdx.x;
    int b   = bid >> 6;
    int k   = bid & (NCHUNKS-1);
    int cs  = k * CHUNK;

    const uint32_t* src = (const uint32_t*)(bp + (size_t)b * L * NC + (size_t)cs * NC);
    for (int i = l; i < CHUNK*NC/4; i += 64) lds4[i] = src[i];
    __syncthreads();
    const uint8_t* lb = (const uint8_t*)lds4;

    // phase 2: segment tables (chunk 0 seg 0 crosses t=0: its result is never used)
    int c0 = l, c1 = l + 63, c2 = l + 126;
    bool v2 = (c2 < 8*NC);
    int t0 = c0 % NC, t1 = c1 % NC, t2 = v2 ? (c2 % NC) : 0;
    int r0 = (c0 / NC) * 32, r1 = (c1 / NC) * 32, r2 = v2 ? (c2 / NC) * 32 : 0;
    for (int i = 31; i >= 0; --i) {
        t0 = lb[(r0+i)*NC + t0];
        t1 = lb[(r1+i)*NC + t1];
        if (v2) t2 = lb[(r2+i)*NC + t2];
    }
    segJ[c0] = (uint8_t)(t0 & 31);           // mask: chunk-0/seg-0 garbage stays in-bounds
    segJ[c1] = (uint8_t)(t1 & 31);
    if (v2) segJ[c2] = (uint8_t)(t2 & 31);
    __syncthreads();

    // phase 3: compose segment entry tags E[s] = tag at position cs + 32s + 31
    if (l == 0) {
        int tag = ent[b * NCHUNKS + k];              // exact tag at ce-1
        E[7] = (uint8_t)tag;
        #pragma unroll
        for (int s = 7; s >= 1; --s) { tag = segJ[s*NC + tag]; E[s-1] = (uint8_t)tag; }
    }
    __syncthreads();

    // phase 4: 8 lanes re-walk their 32 rows
    if (l < 8) {
        int tag = E[l];
        int rb  = l * 32;
        for (int i = 31; i >= 0; --i) {              // t = cs+rb+i down to cs+rb
            tags[rb + i] = tag;
            tag = lb[(rb+i)*NC + tag];               // hop at t=0 (chunk 0) unused
        }
    }
    __syncthreads();

    int4* ob = (int4*)(out + (size_t)b * L + cs);
    ob[l] = ((const int4*)tags)[l];                  // 64 lanes x int4 = 256 ints
}

extern "C" void kernel_launch(void* const* d_in, const int* in_sizes, int n_in,
                              void* d_out, int out_size, void* d_ws, size_t ws_size,
                              hipStream_t stream) {
    const float* x  = (const float*)d_in[0];
    const float* w1 = (const float*)d_in[1];
    const float* b1 = (const float*)d_in[2];
    const float* w2 = (const float*)d_in[3];
    const float* b2 = (const float*)d_in[4];
    const float* st = (const float*)d_in[5];
    const float* en = (const float*)d_in[6];
    const float* tr = (const float*)d_in[7];
    int* out = (int*)d_out;

    char* ws = (char*)d_ws;
    float*   em = (float*)ws;                                    // em_T: 22,020,096 B
    float*   sc = (float*)(ws + (size_t)NB*L*NC*4);              // packed scores: 22,020,096 B
    uint8_t* bp = (uint8_t*)(ws + (size_t)NB*L*NC*8);            // 5,505,024 B
    int*     lt = (int*)(ws + (size_t)NB*L*NC*9);                // int[NB]
    // J/ent alias the em region: em is dead after k_bp completes (stream-ordered).
    uint8_t* J   = (uint8_t*)ws;                                 // NB*64*21 = 21,504 B
    uint8_t* ent = (uint8_t*)ws + 21504;                         // NB*64 = 1,024 B

    k_conv  <<<dim3(NB*L/256),       dim3(256), 0, stream>>>(x, w1, b1, w2, b2, em);
    k_scores<<<dim3(NB),             dim3(64),  0, stream>>>(em, st, en, tr, sc, lt);
    k_bp    <<<dim3(NB*128),         dim3(256), 0, stream>>>(em, sc, tr, bp);
    k_jump  <<<dim3(NB*(NCHUNKS-1)), dim3(64),  0, stream>>>(bp, J);
    k_seq   <<<dim3(1),              dim3(64),  0, stream>>>(J, lt, ent);
    k_out   <<<dim3(NB*NCHUNKS),     dim3(64),  0, stream>>>(bp, ent, out);
}

// Round 2
// 2737.780 us; speedup vs baseline: 1.1884x; 1.1884x over previous
//
#include <hip/hip_runtime.h>
#include <stdint.h>

#define NB 16
#define HH 128
#define WW 128
#define L (HH*WW)        // 16384
#define CIN 3
#define HID 256
#define NC 21
#define CHUNK 256
#define NCHUNKS (L/CHUNK)   // 64
#define T_PER 32            // t's per wave in k_bp
#define NPACK (L/4)         // 4096 packs of 4 timesteps

// ---------------- K1: conv -> fp32 emissions, TRANSPOSED em_T[b][c][t], LDS input tile ----------------
// fp64 accumulate (round once to fp32 = correctly rounded), fp32 elementwise bias in ref order.
__global__ __launch_bounds__(256) void k_conv(
    const float* __restrict__ x, const float* __restrict__ w1,
    const float* __restrict__ b1, const float* __restrict__ w2,
    const float* __restrict__ b2, float* __restrict__ emT)
{
    __shared__ float xs[CIN*4*WW];        // 3 ic x 4 rows x 128 cols = 6144 B
    int tid = threadIdx.x;
    int g  = blockIdx.x * 256 + tid;      // 0..B*L-1
    int b  = g >> 14;
    int t0 = (blockIdx.x * 256) & (L-1);  // first t of block (multiple of 256)
    int y0 = t0 >> 7;                     // first of the block's 2 rows
    int dy = tid >> 7;                    // 0 or 1
    int xx = tid & (WW-1);
    int t  = t0 + tid;

    const float* xb = x + (size_t)b * CIN * L;
    for (int i = tid; i < CIN*4*WW; i += 256) {
        int ic  = i >> 9;                 // /512
        int rem = i & 511;
        int rr  = rem >> 7;               // 0..3
        int cc  = rem & 127;
        int row = y0 - 1 + rr;
        xs[i] = (row >= 0 && row < HH) ? xb[ic*L + (row<<7) + cc] : 0.f;
    }
    __syncthreads();

    double p[27];
    #pragma unroll
    for (int ic = 0; ic < CIN; ++ic) {
        #pragma unroll
        for (int ky = 0; ky < 3; ++ky) {
            #pragma unroll
            for (int kx = 0; kx < 3; ++kx) {
                int xc = xx + kx - 1;
                float v = (xc >= 0 && xc < WW) ? xs[ic*512 + (dy+ky)*128 + xc] : 0.f;
                p[ic*9 + ky*3 + kx] = (double)v;
            }
        }
    }

    double acc[NC];
    #pragma unroll
    for (int c = 0; c < NC; ++c) acc[c] = 0.0;

    #pragma unroll 2
    for (int oc = 0; oc < HID; ++oc) {
        double hv = 0.0;                              // conv1 accum
        #pragma unroll
        for (int j = 0; j < 27; ++j) hv += (double)w1[oc*27 + j] * p[j];
        float h32 = (float)hv;                        // round conv1 to fp32
        h32 = h32 + b1[oc];                           // fp32 elementwise bias
        h32 = fmaxf(h32, 0.f);                        // relu (fp32)
        double hd = (double)h32;
        #pragma unroll
        for (int c = 0; c < NC; ++c) acc[c] += (double)w2[c*HID + oc] * hd;
    }
    float* dstb = emT + (size_t)b * NC * L;
    #pragma unroll
    for (int c = 0; c < NC; ++c) {
        float e32 = (float)acc[c];                    // round conv2 to fp32
        dstb[(size_t)c * L + t] = e32 + b2[c];        // transposed store (coalesced in t)
    }
}

// ---------------- K2a: single-DS-level recursion: 11 bpermute + permlane32_swap combine ----------------
// s'[n] = fl( max_p fl(s[p]+T[p][n]) + e[n] ) — bitwise equal to ref by RNE monotonicity.
// R11 (9 bpermute, TWO dependent DS levels) = 314 cy/step; readlane (R1) = 421 cy/step (SGPR
// path doesn't pipeline, ~15 cy/readlane serialized). This version: ONE DS level (11 bpermutes,
// groups of lanes 0-20 / 32-52 each gather half the p's) + VALU-pipe cross-half combine via
// v_permlane32_swap (~4 cy, no DS round trip). pr = fmax of BOTH swap results -> every lane
// holds the exact 21-way max, immune to result-order semantics. Est ~180-250 cy/step.
typedef int iv2 __attribute__((ext_vector_type(2)));

__global__ __launch_bounds__(64) void k_scores(
    const float* __restrict__ emT, const float* __restrict__ start,
    const float* __restrict__ endt, const float* __restrict__ trans,
    float* __restrict__ sc, int* __restrict__ last_tag)
{
    __shared__ float fin[NC];
    int l = threadIdx.x;
    int b = blockIdx.x;
    int u = l & 31;
    int g = l >> 5;                        // 0: lanes 0-31, 1: lanes 32-63
    int n = u < NC ? u : NC-1;             // lanes 21-31 / 53-63 shadow n=20 (never sourced)

    const float4* er4 = (const float4*)(emT + ((size_t)b * NC + n) * L);
    float*        scp = sc + (size_t)b * NC * L;          // 84 floats per pack

    // group g handles p in Pg: P0 = {0..10}, P1 = {11..20} (+dup p=20 for op 10)
    float tc[11];
    int   ga[11];
    #pragma unroll
    for (int i = 0; i < 11; ++i) {
        int p = g ? (11 + i) : i;
        if (p > 20) p = 20;                // g=1 op 10 duplicates p=20 (exact: dup in max)
        tc[i] = trans[p*NC + n];
        ga[i] = p * 4;                     // bpermute sources: canonical state in lanes 0..20
    }
    #pragma unroll
    for (int i = 0; i < 11; ++i) asm volatile("" : "+v"(tc[i]));   // pin in VGPRs
    #pragma unroll
    for (int i = 0; i < 11; ++i) asm volatile("" : "+v"(ga[i]));

    float sv;   // current score: lane n (and n+32) holds s[n]

    #define BPERM(A,V) __int_as_float(__builtin_amdgcn_ds_bpermute((A), __float_as_int(V)))

    #define STEP(EV, OUT) { \
        float w0  = BPERM(ga[0],  sv) + tc[0];  \
        float w1  = BPERM(ga[1],  sv) + tc[1];  \
        float w2  = BPERM(ga[2],  sv) + tc[2];  \
        float w3  = BPERM(ga[3],  sv) + tc[3];  \
        float w4  = BPERM(ga[4],  sv) + tc[4];  \
        float w5  = BPERM(ga[5],  sv) + tc[5];  \
        float w6  = BPERM(ga[6],  sv) + tc[6];  \
        float w7  = BPERM(ga[7],  sv) + tc[7];  \
        float w8  = BPERM(ga[8],  sv) + tc[8];  \
        float w9  = BPERM(ga[9],  sv) + tc[9];  \
        float w10 = BPERM(ga[10], sv) + tc[10]; \
        float m0 = fmaxf(fmaxf(w0, w1), w2);    /* v_max3 */ \
        float m1 = fmaxf(fmaxf(w3, w4), w5);    \
        float m2 = fmaxf(fmaxf(w6, w7), w8);    \
        float m3 = fmaxf(w9, w10);              \
        float pm = fmaxf(fmaxf(fmaxf(m0, m1), m2), m3);   /* partial max over my half */ \
        iv2 rr = __builtin_amdgcn_permlane32_swap(__float_as_int(pm), __float_as_int(pm), false, false); \
        float pr = fmaxf(__int_as_float(rr[0]), __int_as_float(rr[1]));  /* exact max over 21, all lanes */ \
        OUT = pr + (EV);                        /* fl(+e) */ \
        sv = OUT; }

    float4 ebuf0 = er4[0];
    float4 ebuf1 = er4[1];

    // ---- pack 0 (t=0 init + t=1..3) ----
    float v0 = ebuf0.x + start[n];      // s0 = fl(em[0]+start), ref order
    sv = v0;
    {
        float4 ev = ebuf0;
        ebuf0 = er4[2];
        float a1v, a2v, a3v;
        STEP(ev.y, a1v)
        STEP(ev.z, a2v)
        STEP(ev.w, a3v)
        if (l < NC) *(float4*)(scp + n*4) = make_float4(v0, a1v, a2v, a3v);
    }

    // ---- packs 1..4095 ----
    for (int k = 1; k < NPACK; ++k) {
        float4 ev = (k & 1) ? ebuf1 : ebuf0;
        int kp = k + 2; if (kp > NPACK-1) kp = NPACK-1;
        if (k & 1) ebuf1 = er4[kp]; else ebuf0 = er4[kp];

        float b0, b1_, b2_, b3;
        STEP(ev.x, b0)
        STEP(ev.y, b1_)
        STEP(ev.z, b2_)
        STEP(ev.w, b3)
        if (l < NC) *(float4*)(scp + k*84 + n*4) = make_float4(b0, b1_, b2_, b3);
    }
    #undef STEP
    #undef BPERM

    if (l < NC) fin[n] = sv;
    __syncthreads();
    if (l == 0) {
        float bv = fin[0] + endt[0]; int bt = 0;
        #pragma unroll
        for (int j = 1; j < NC; ++j) {
            float v = fin[j] + endt[j];
            if (v > bv) { bv = v; bt = j; }
        }
        last_tag[b] = bt;
    }
}

// ---------------- K2b: parallel backpointer recovery ----------------
// bp[t][n] = first p with fl(fl(s_{t-1}[p]+T[p][n])+e[t][n]) == s_t[n]
__global__ __launch_bounds__(256) void k_bp(
    const float* __restrict__ emT, const float* __restrict__ sc,
    const float* __restrict__ trans, uint8_t* __restrict__ bp)
{
    int wave = threadIdx.x >> 6;
    int lane = threadIdx.x & 63;
    int ne   = lane < NC ? lane : NC-1;

    int bidx  = blockIdx.x;
    int b     = bidx >> 7;                              // 128 blocks per batch
    int tbase = (bidx & 127) * (4*T_PER) + wave*T_PER;

    const float* emb = emT + (size_t)b * NC * L;
    const float* scp = sc  + (size_t)b * NC * L;
    uint8_t*     bpb = bp  + (size_t)b * L * NC;

    float tc[NC];
    #pragma unroll
    for (int pp = 0; pp < NC; ++pp) tc[pp] = trans[pp*NC + ne];

    for (int t = tbase; t < tbase + T_PER; ++t) {
        if (t == 0) continue;
        float target = scp[(t>>2)*84 + ne*4 + (t&3)];
        float e      = emb[(size_t)ne * L + t];
        const float* sp = scp + ((t-1)>>2)*84 + ((t-1)&3);
        int fi = 0;
        #pragma unroll
        for (int pp = NC-1; pp >= 0; --pp) {
            float cand = (sp[pp*4] + tc[pp]) + e;
            if (cand == target) fi = pp;
        }
        if (lane < NC) bpb[(size_t)t * NC + ne] = (uint8_t)fi;
    }
}

// ---------------- K3a: per-chunk jump tables, SEGMENTED chase (exact) ----------------
__global__ __launch_bounds__(64) void k_jump(
    const uint8_t* __restrict__ bp, uint8_t* __restrict__ J)
{
    __shared__ uint32_t lds4[CHUNK*NC/4];    // 5376 B of bp rows [cs..ce)
    __shared__ uint8_t  segJ[8*NC];          // 168 B
    int l   = threadIdx.x;
    int bid = blockIdx.x;
    int b   = bid / (NCHUNKS-1);
    int k   = bid % (NCHUNKS-1) + 1;         // chunks 1..63
    int cs  = k * CHUNK;

    const uint32_t* src = (const uint32_t*)(bp + (size_t)b * L * NC + (size_t)cs * NC);
    for (int i = l; i < CHUNK*NC/4; i += 64) lds4[i] = src[i];
    __syncthreads();
    const uint8_t* lb = (const uint8_t*)lds4;

    // 168 = 8 segs x 21 hyps; chase c -> (s=c/21, h=c%21), rows s*32+31 .. s*32
    int c0 = l, c1 = l + 63, c2 = l + 126;
    bool v2 = (c2 < 8*NC);
    int t0 = c0 % NC, t1 = c1 % NC, t2 = v2 ? (c2 % NC) : 0;
    int r0 = (c0 / NC) * 32, r1 = (c1 / NC) * 32, r2 = v2 ? (c2 / NC) * 32 : 0;
    for (int i = 31; i >= 0; --i) {          // 3 independent chains -> pipelined
        t0 = lb[(r0+i)*NC + t0];
        t1 = lb[(r1+i)*NC + t1];
        if (v2) t2 = lb[(r2+i)*NC + t2];
    }
    segJ[c0] = (uint8_t)t0;
    segJ[c1] = (uint8_t)t1;
    if (v2) segJ[c2] = (uint8_t)t2;
    __syncthreads();

    if (l < NC) {
        int tag = l;
        #pragma unroll
        for (int s = 7; s >= 0; --s) tag = segJ[s*NC + tag];
        J[((size_t)b * NCHUNKS + k) * NC + l] = (uint8_t)tag;
    }
}

// ---------------- K3b: thread chunk entries through jump tables (LDS-staged J) ----------------
__global__ __launch_bounds__(64) void k_seq(
    const uint8_t* __restrict__ J, const int* __restrict__ last_tag,
    uint8_t* __restrict__ ent)
{
    __shared__ uint32_t ldsJ4[NB*NCHUNKS*NC/4];   // 21504 B
    int l = threadIdx.x;
    const uint32_t* src = (const uint32_t*)J;
    for (int i = l; i < NB*NCHUNKS*NC/4; i += 64) ldsJ4[i] = src[i];
    __syncthreads();
    const uint8_t* lj = (const uint8_t*)ldsJ4;

    if (l < NB) {
        int b = l;
        int tag = last_tag[b];                       // tag at t = L-1
        ent[b * NCHUNKS + 63] = (uint8_t)tag;
        for (int k = NCHUNKS-1; k >= 1; --k) {
            tag = lj[((size_t)b * NCHUNKS + k) * NC + tag];
            ent[b * NCHUNKS + (k-1)] = (uint8_t)tag;
        }
    }
}

// ---------------- K3c: per-chunk output, SEGMENTED re-walk from exact seed ----------------
__global__ __launch_bounds__(64) void k_out(
    const uint8_t* __restrict__ bp, const uint8_t* __restrict__ ent,
    int* __restrict__ out)
{
    __shared__ uint32_t lds4[CHUNK*NC/4];
    __shared__ uint8_t  segJ[8*NC];
    __shared__ uint8_t  E[8];
    __shared__ int      tags[CHUNK];
    int l   = threadIdx.x;
    int bid = blockIdx.x;
    int b   = bid >> 6;
    int k   = bid & (NCHUNKS-1);
    int cs  = k * CHUNK;

    const uint32_t* src = (const uint32_t*)(bp + (size_t)b * L * NC + (size_t)cs * NC);
    for (int i = l; i < CHUNK*NC/4; i += 64) lds4[i] = src[i];
    __syncthreads();
    const uint8_t* lb = (const uint8_t*)lds4;

    // phase 2: segment tables (chunk 0 seg 0 crosses t=0: its result is never used)
    int c0 = l, c1 = l + 63, c2 = l + 126;
    bool v2 = (c2 < 8*NC);
    int t0 = c0 % NC, t1 = c1 % NC, t2 = v2 ? (c2 % NC) : 0;
    int r0 = (c0 / NC) * 32, r1 = (c1 / NC) * 32, r2 = v2 ? (c2 / NC) * 32 : 0;
    for (int i = 31; i >= 0; --i) {
        t0 = lb[(r0+i)*NC + t0];
        t1 = lb[(r1+i)*NC + t1];
        if (v2) t2 = lb[(r2+i)*NC + t2];
    }
    segJ[c0] = (uint8_t)(t0 & 31);           // mask: chunk-0/seg-0 garbage stays in-bounds
    segJ[c1] = (uint8_t)(t1 & 31);
    if (v2) segJ[c2] = (uint8_t)(t2 & 31);
    __syncthreads();

    // phase 3: compose segment entry tags E[s] = tag at position cs + 32s + 31
    if (l == 0) {
        int tag = ent[b * NCHUNKS + k];              // exact tag at ce-1
        E[7] = (uint8_t)tag;
        #pragma unroll
        for (int s = 7; s >= 1; --s) { tag = segJ[s*NC + tag]; E[s-1] = (uint8_t)tag; }
    }
    __syncthreads();

    // phase 4: 8 lanes re-walk their 32 rows
    if (l < 8) {
        int tag = E[l];
        int rb  = l * 32;
        for (int i = 31; i >= 0; --i) {              // t = cs+rb+i down to cs+rb
            tags[rb + i] = tag;
            tag = lb[(rb+i)*NC + tag];               // hop at t=0 (chunk 0) unused
        }
    }
    __syncthreads();

    int4* ob = (int4*)(out + (size_t)b * L + cs);
    ob[l] = ((const int4*)tags)[l];                  // 64 lanes x int4 = 256 ints
}

extern "C" void kernel_launch(void* const* d_in, const int* in_sizes, int n_in,
                              void* d_out, int out_size, void* d_ws, size_t ws_size,
                              hipStream_t stream) {
    const float* x  = (const float*)d_in[0];
    const float* w1 = (const float*)d_in[1];
    const float* b1 = (const float*)d_in[2];
    const float* w2 = (const float*)d_in[3];
    const float* b2 = (const float*)d_in[4];
    const float* st = (const float*)d_in[5];
    const float* en = (const float*)d_in[6];
    const float* tr = (const float*)d_in[7];
    int* out = (int*)d_out;

    char* ws = (char*)d_ws;
    float*   em = (float*)ws;                                    // em_T: 22,020,096 B
    float*   sc = (float*)(ws + (size_t)NB*L*NC*4);              // packed scores: 22,020,096 B
    uint8_t* bp = (uint8_t*)(ws + (size_t)NB*L*NC*8);            // 5,505,024 B
    int*     lt = (int*)(ws + (size_t)NB*L*NC*9);                // int[NB]
    // J/ent alias the em region: em is dead after k_bp completes (stream-ordered).
    uint8_t* J   = (uint8_t*)ws;                                 // NB*64*21 = 21,504 B
    uint8_t* ent = (uint8_t*)ws + 21504;                         // NB*64 = 1,024 B

    k_conv  <<<dim3(NB*L/256),       dim3(256), 0, stream>>>(x, w1, b1, w2, b2, em);
    k_scores<<<dim3(NB),             dim3(64),  0, stream>>>(em, st, en, tr, sc, lt);
    k_bp    <<<dim3(NB*128),         dim3(256), 0, stream>>>(em, sc, tr, bp);
    k_jump  <<<dim3(NB*(NCHUNKS-1)), dim3(64),  0, stream>>>(bp, J);
    k_seq   <<<dim3(1),              dim3(64),  0, stream>>>(J, lt, ent);
    k_out   <<<dim3(NB*NCHUNKS),     dim3(64),  0, stream>>>(bp, ent, out);
}